// Round 1
// baseline (2950.094 us; speedup 1.0000x reference)
//
#include <hip/hip_runtime.h>
#include <hip/hip_bf16.h>

typedef __bf16  bf16x8  __attribute__((ext_vector_type(8)));
typedef short   short8_t __attribute__((ext_vector_type(8)));
typedef float   float4_t __attribute__((ext_vector_type(4)));

#define MFMA(a, b, c) __builtin_amdgcn_mfma_f32_16x16x32_bf16((a), (b), (c), 0, 0, 0)

__device__ __forceinline__ unsigned short f2bf(float f) {
  unsigned u = __builtin_bit_cast(unsigned, f);
  unsigned r = ((u >> 16) & 1u) + 0x7FFFu;   // round-to-nearest-even
  return (unsigned short)((u + r) >> 16);
}
__device__ __forceinline__ float sigf(float x) {
  return __builtin_amdgcn_rcpf(1.f + __expf(-x));
}
__device__ __forceinline__ float tanh_fast(float x) {
  return 1.f - 2.f * __builtin_amdgcn_rcpf(1.f + __expf(2.f * x));
}

// Grid: B/32 blocks (256), 512 threads (8 waves). Wave w owns hidden units
// [16w, 16w+16): gate columns {g*128 + 16w + j} for g = i,f,g,o. All MFMA
// fragments (A and B) use layout: 16-lane index = row/col, (lane>>4, e) = k.
// LDS h/x staging is fragment-linear -> all ds_read_b128 conflict-free.
__global__ __launch_bounds__(512, 2) void lstm_roll(
    const float* __restrict__ x0,  const float* __restrict__ W0,
    const float* __restrict__ b0v, const float* __restrict__ W1,
    const float* __restrict__ b1v, const float* __restrict__ Wout,
    const float* __restrict__ bout, const float* __restrict__ dts,
    const int* __restrict__ nsp,   float* __restrict__ out)
{
  __shared__ __align__(16) unsigned short w0h[8 * 4 * 4 * 512];  // 128 KiB: W0 h-part B-frags [w][g][kt][lane*8+e]
  __shared__ __align__(16) unsigned short woutF[2 * 4 * 512];    //   8 KiB: Wout B-frags [n][kt]
  __shared__ __align__(16) unsigned short h0f[4 * 2 * 512];      //   8 KiB: h0 A-frags [kt][m]
  __shared__ __align__(16) unsigned short h1f[4 * 2 * 512];      //   8 KiB: h1 A-frags [kt][m]
  __shared__ __align__(16) unsigned short xf[2 * 512];           //   2 KiB: x  A-frags [m]

  const int tid = threadIdx.x;
  const int w   = tid >> 6;        // wave 0..7
  const int l   = tid & 63;        // lane
  const int lm  = l & 15;          // row/col within 16
  const int lh  = l >> 4;          // k-block / row-group
  const int T   = nsp[0];
  const long rowStride = (long)(T + 1) * 32;
  const long bbase = (long)blockIdx.x * 32;

  // ---------------- weight gather / packing (once) ----------------
  bf16x8 w0x[4];       // W0 x-part B-frags, K=32
  bf16x8 w1f[4][8];    // W1 B-frags, K=256 (kt 0..3 = h0-part, 4..7 = h1-part)
  #pragma unroll
  for (int g = 0; g < 4; ++g) {
    const int col = g * 128 + w * 16 + lm;
    {
      short8_t t8;
      #pragma unroll
      for (int e = 0; e < 8; ++e) t8[e] = (short)f2bf(W0[(lh * 8 + e) * 512 + col]);
      w0x[g] = __builtin_bit_cast(bf16x8, t8);
    }
    #pragma unroll
    for (int kt = 0; kt < 8; ++kt) {
      short8_t t8;
      #pragma unroll
      for (int e = 0; e < 8; ++e) t8[e] = (short)f2bf(W1[(kt * 32 + lh * 8 + e) * 512 + col]);
      w1f[g][kt] = __builtin_bit_cast(bf16x8, t8);
    }
    #pragma unroll
    for (int kt = 0; kt < 4; ++kt) {
      const int base = (((w * 4 + g) * 4) + kt) * 512 + l * 8;
      #pragma unroll
      for (int e = 0; e < 8; ++e)
        w0h[base + e] = f2bf(W0[(32 + kt * 32 + lh * 8 + e) * 512 + col]);
    }
  }
  { // Wout B-frags: 8 frags total, one gathered per wave
    const int n = w & 1, kt = w >> 1;  // kt 0..3 for w<8? w>>1 in 0..3
    if (kt < 4) {
      const int base = (n * 4 + kt) * 512 + l * 8;
      #pragma unroll
      for (int e = 0; e < 8; ++e)
        woutF[base + e] = f2bf(Wout[(kt * 32 + lh * 8 + e) * 32 + (n * 16 + lm)]);
    }
  }
  float b0r[4], b1r[4];
  #pragma unroll
  for (int g = 0; g < 4; ++g) {
    b0r[g] = b0v[g * 128 + w * 16 + lm];
    b1r[g] = b1v[g * 128 + w * 16 + lm];
  }

  // phase-C (projection) mapping: waves 0..3 own (m_c, n_c) output quadrant
  const int m_c = w & 1, n_c = (w >> 1) & 1;
  float boutr = 0.f, dtsr = 0.f, xr[4] = {0.f, 0.f, 0.f, 0.f};
  long obase0 = 0;
  int  xfbase = 0;
  if (w < 4) {
    boutr = bout[n_c * 16 + lm];
    dtsr  = dts [n_c * 16 + lm] * 0.01f;                 // fold DT
    const int kin = n_c * 16 + lm;                       // k index within K=32 x-tile
    xfbase = m_c * 512 + (lh * 4 + 16 * (kin >> 3)) * 8 + (kin & 7);
    obase0 = (bbase + m_c * 16 + lh * 4) * rowStride + (n_c * 16 + lm);
    #pragma unroll
    for (int r = 0; r < 4; ++r) {
      xr[r] = x0[(bbase + m_c * 16 + lh * 4 + r) * 32 + n_c * 16 + lm];
      out[obase0 + r * rowStride] = xr[r];               // trajectory t = 0
      xf[xfbase + r * 8] = f2bf(xr[r]);
    }
  }
  for (int i = tid; i < 4 * 2 * 512; i += 512) { h0f[i] = 0; h1f[i] = 0; }

  // h-write scatter base into fragment layout (same for h0f/h1f):
  // value h[16m + 4*lh + r][16w + lm] -> frag kt=w>>1, lane' = (4lh+r) + 16*(k_in>>3), e = k_in&7
  const int hwb = ((w >> 1) * 2) * 512 +
                  (lh * 4 + 16 * (2 * (w & 1) + ((lm >> 3) & 1))) * 8 + (lm & 7);

  float4_t c0[2], c1[2];
  #pragma unroll
  for (int m = 0; m < 2; ++m) {
    c0[m] = (float4_t){0.f, 0.f, 0.f, 0.f};
    c1[m] = (float4_t){0.f, 0.f, 0.f, 0.f};
  }

  __syncthreads();

  #pragma unroll 1
  for (int t = 0; t < T; ++t) {
    // ---------------- cell 0: gates = [x, h0] @ W0 + b0 ----------------
    float4_t acc[2][4];
    #pragma unroll
    for (int m = 0; m < 2; ++m)
      #pragma unroll
      for (int g = 0; g < 4; ++g)
        acc[m][g] = (float4_t){b0r[g], b0r[g], b0r[g], b0r[g]};
    {
      const bf16x8 a0 = *(const bf16x8*)&xf[l * 8];
      const bf16x8 a1 = *(const bf16x8*)&xf[512 + l * 8];
      #pragma unroll
      for (int g = 0; g < 4; ++g) {
        acc[0][g] = MFMA(a0, w0x[g], acc[0][g]);
        acc[1][g] = MFMA(a1, w0x[g], acc[1][g]);
      }
    }
    #pragma unroll
    for (int kt = 0; kt < 4; ++kt) {
      const bf16x8 a0 = *(const bf16x8*)&h0f[(kt * 2 + 0) * 512 + l * 8];
      const bf16x8 a1 = *(const bf16x8*)&h0f[(kt * 2 + 1) * 512 + l * 8];
      #pragma unroll
      for (int g = 0; g < 4; ++g) {
        const bf16x8 bw = *(const bf16x8*)&w0h[(((w * 4 + g) * 4) + kt) * 512 + l * 8];
        acc[0][g] = MFMA(a0, bw, acc[0][g]);
        acc[1][g] = MFMA(a1, bw, acc[1][g]);
      }
    }
    float4_t h0n[2];
    #pragma unroll
    for (int m = 0; m < 2; ++m)
      #pragma unroll
      for (int r = 0; r < 4; ++r) {
        const float iv = sigf(acc[m][0][r]);
        const float fv = sigf(acc[m][1][r]);
        const float gv = tanh_fast(acc[m][2][r]);
        const float ov = sigf(acc[m][3][r]);
        const float cc = fv * c0[m][r] + iv * gv;
        c0[m][r] = cc;
        h0n[m][r] = ov * tanh_fast(cc);
      }
    __syncthreads();                                   // (1) all h0f/xf reads done
    #pragma unroll
    for (int m = 0; m < 2; ++m)
      #pragma unroll
      for (int r = 0; r < 4; ++r)
        h0f[hwb + m * 512 + r * 8] = f2bf(h0n[m][r]);
    __syncthreads();                                   // (2) h0f (new) published

    // ---------------- cell 1: gates = [h0n, h1] @ W1 + b1 ----------------
    #pragma unroll
    for (int m = 0; m < 2; ++m)
      #pragma unroll
      for (int g = 0; g < 4; ++g)
        acc[m][g] = (float4_t){b1r[g], b1r[g], b1r[g], b1r[g]};
    #pragma unroll
    for (int kt = 0; kt < 8; ++kt) {
      const unsigned short* src = (kt < 4) ? &h0f[(kt * 2) * 512] : &h1f[((kt - 4) * 2) * 512];
      const bf16x8 a0 = *(const bf16x8*)&src[l * 8];
      const bf16x8 a1 = *(const bf16x8*)&src[512 + l * 8];
      #pragma unroll
      for (int g = 0; g < 4; ++g) {
        acc[0][g] = MFMA(a0, w1f[g][kt], acc[0][g]);
        acc[1][g] = MFMA(a1, w1f[g][kt], acc[1][g]);
      }
    }
    float4_t h1n[2];
    #pragma unroll
    for (int m = 0; m < 2; ++m)
      #pragma unroll
      for (int r = 0; r < 4; ++r) {
        const float iv = sigf(acc[m][0][r]);
        const float fv = sigf(acc[m][1][r]);
        const float gv = tanh_fast(acc[m][2][r]);
        const float ov = sigf(acc[m][3][r]);
        const float cc = fv * c1[m][r] + iv * gv;
        c1[m][r] = cc;
        h1n[m][r] = ov * tanh_fast(cc);
      }
    __syncthreads();                                   // (3) all h1f reads done
    #pragma unroll
    for (int m = 0; m < 2; ++m)
      #pragma unroll
      for (int r = 0; r < 4; ++r)
        h1f[hwb + m * 512 + r * 8] = f2bf(h1n[m][r]);
    __syncthreads();                                   // (4) h1f (new) published

    // ---------------- projection: x += (h1n @ Wout + bout) * dt_scale * DT ----------------
    if (w < 4) {
      float4_t dacc = (float4_t){boutr, boutr, boutr, boutr};
      #pragma unroll
      for (int kt = 0; kt < 4; ++kt) {
        const bf16x8 a  = *(const bf16x8*)&h1f[(kt * 2 + m_c) * 512 + l * 8];
        const bf16x8 bw = *(const bf16x8*)&woutF[(n_c * 4 + kt) * 512 + l * 8];
        dacc = MFMA(a, bw, dacc);
      }
      #pragma unroll
      for (int r = 0; r < 4; ++r) {
        xr[r] += dacc[r] * dtsr;
        xf[xfbase + r * 8] = f2bf(xr[r]);
      }
    }
    __syncthreads();                                   // (5) xf (new) published
    if (w < 4) {                                       // global stores drain during next cell0
      const long ob = obase0 + (long)(t + 1) * 32;
      #pragma unroll
      for (int r = 0; r < 4; ++r) out[ob + r * rowStride] = xr[r];
    }
  }
}

extern "C" void kernel_launch(void* const* d_in, const int* in_sizes, int n_in,
                              void* d_out, int out_size, void* d_ws, size_t ws_size,
                              hipStream_t stream) {
  (void)n_in; (void)out_size; (void)d_ws; (void)ws_size;
  const float* x0   = (const float*)d_in[0];
  const float* W0   = (const float*)d_in[1];
  const float* b0   = (const float*)d_in[2];
  const float* W1   = (const float*)d_in[3];
  const float* b1   = (const float*)d_in[4];
  const float* Wout = (const float*)d_in[5];
  const float* bout = (const float*)d_in[6];
  const float* dts  = (const float*)d_in[7];
  const int*   nsp  = (const int*)d_in[8];
  float* out = (float*)d_out;

  const int B    = in_sizes[0] / 32;   // 8192
  const int grid = B / 32;             // 256 blocks, 32 batch rows each
  lstm_roll<<<dim3(grid), dim3(512), 0, stream>>>(x0, W0, b0, W1, b1, Wout, bout, dts, nsp, out);
}